// Round 1
// baseline (109.328 us; speedup 1.0000x reference)
//
#include <hip/hip_runtime.h>
#include <hip/hip_bf16.h>

#define BN 4096
#define DD 128

typedef __bf16 bf16x8 __attribute__((ext_vector_type(8)));
typedef float f32x16 __attribute__((ext_vector_type(16)));

// ---------------- prep: f32 -> bf16 (with gather), diag dots, zero accums ----
__global__ __launch_bounds__(64) void prep_kernel(
    const float* __restrict__ z1, const float* __restrict__ z2,
    const float* __restrict__ attr, const int* __restrict__ uni,
    __hip_bfloat16* __restrict__ Z1b, __hip_bfloat16* __restrict__ Z2b,
    __hip_bfloat16* __restrict__ G1b, __hip_bfloat16* __restrict__ G2b,
    __hip_bfloat16* __restrict__ Ab,
    float* __restrict__ d1, float* __restrict__ d2, float* __restrict__ d3,
    float* __restrict__ S1, float* __restrict__ S2, float* __restrict__ out)
{
    int r = blockIdx.x;
    int t = threadIdx.x;
    int gid = r * 64 + t;
    if (gid < 4 * BN) { S1[gid] = 0.f; S2[gid] = 0.f; }
    if (gid == 0) out[0] = 0.f;

    int au = uni[r];
    float p1 = 0.f, p2 = 0.f, p3 = 0.f;
    #pragma unroll
    for (int e = t; e < DD; e += 64) {
        float v1 = z1[(size_t)r * DD + e];
        float v2 = z2[(size_t)r * DD + e];
        float ga = attr[(size_t)au * DD + e];
        float g1 = z1[(size_t)au * DD + e];
        float g2 = z2[(size_t)au * DD + e];
        Z1b[(size_t)r * DD + e] = __float2bfloat16(v1);
        Z2b[(size_t)r * DD + e] = __float2bfloat16(v2);
        G1b[(size_t)r * DD + e] = __float2bfloat16(g1);
        G2b[(size_t)r * DD + e] = __float2bfloat16(g2);
        Ab [(size_t)r * DD + e] = __float2bfloat16(ga);
        p1 += g1 * ga; p2 += g2 * ga; p3 += v1 * v2;
    }
    #pragma unroll
    for (int m = 1; m < 64; m <<= 1) {
        p1 += __shfl_xor(p1, m);
        p2 += __shfl_xor(p2, m);
        p3 += __shfl_xor(p3, m);
    }
    if (t == 0) { d1[r] = p1; d2[r] = p2; d3[r] = p3; }
}

// ---------------- rowsum: fused sim + exp row-sum over 4 jobs ----------------
// job 0: X=G1b vs Y=Ab        (4096 cols)
// job 1: X=G2b vs Y=Ab        (4096 cols)
// job 2: X=Z1b vs Y={Z1b,Z2b} (8192 cols)
// job 3: X=Z2b vs Y={Z1b,Z2b} (8192 cols)
// Each block: 1 wave, 32 X-rows, 1024 columns (one chunk). 24 chunks total.
__global__ __launch_bounds__(64) void rowsum_kernel(
    const __hip_bfloat16* __restrict__ Z1b, const __hip_bfloat16* __restrict__ Z2b,
    const __hip_bfloat16* __restrict__ G1b, const __hip_bfloat16* __restrict__ G2b,
    const __hip_bfloat16* __restrict__ Ab,
    float* __restrict__ S1, float* __restrict__ S2)
{
    int rowblk = blockIdx.x;   // 0..127
    int chunk  = blockIdx.y;   // 0..23

    int job;
    const __hip_bfloat16 *X, *Y;
    int ybase;
    if (chunk < 4)       { job = 0; X = G1b; Y = Ab; ybase = chunk * 1024; }
    else if (chunk < 8)  { job = 1; X = G2b; Y = Ab; ybase = (chunk - 4) * 1024; }
    else if (chunk < 16) { job = 2; X = Z1b; int c = chunk - 8;  ybase = c * 1024;
                           Y = (ybase < BN) ? Z1b : Z2b; if (ybase >= BN) ybase -= BN; }
    else                 { job = 3; X = Z2b; int c = chunk - 16; ybase = c * 1024;
                           Y = (ybase < BN) ? Z1b : Z2b; if (ybase >= BN) ybase -= BN; }

    int lane = threadIdx.x;
    int r = lane & 31, h = lane >> 5;
    int xrow0 = rowblk * 32;

    // A fragments: 8 K-slices of 16, held in registers for the whole sweep.
    // Lane layout for v_mfma_f32_32x32x16_bf16: row = lane&31, k = 16*s + 8*(lane>>5) + j
    const __hip_bfloat16* xrow = X + (size_t)(xrow0 + r) * DD + 8 * h;
    bf16x8 afrag[8];
    #pragma unroll
    for (int s = 0; s < 8; s++)
        afrag[s] = *reinterpret_cast<const bf16x8*>(xrow + 16 * s);

    float acc1[16], acc2[16];
    #pragma unroll
    for (int q = 0; q < 16; q++) { acc1[q] = 0.f; acc2[q] = 0.f; }

    for (int ct = 0; ct < 32; ct++) {          // 32 col-tiles of 32 = 1024 cols
        const __hip_bfloat16* yrow = Y + (size_t)(ybase + ct * 32 + r) * DD + 8 * h;
        f32x16 cacc;
        #pragma unroll
        for (int q = 0; q < 16; q++) cacc[q] = 0.f;
        #pragma unroll
        for (int s = 0; s < 8; s++) {
            bf16x8 bfrag = *reinterpret_cast<const bf16x8*>(yrow + 16 * s);
            cacc = __builtin_amdgcn_mfma_f32_32x32x16_bf16(afrag[s], bfrag, cacc, 0, 0, 0);
        }
        // sim = dot / TEMP = 2*dot ; e1 = exp(sim), e1*e1 = exp(2*sim)
        #pragma unroll
        for (int q = 0; q < 16; q++) {
            float e1 = __expf(2.0f * cacc[q]);
            acc1[q] += e1;
            acc2[q] += e1 * e1;
        }
    }

    // Reduce over the 32 lanes sharing each output row (xor masks < 32 stay in half)
    #pragma unroll
    for (int q = 0; q < 16; q++) {
        float a1 = acc1[q], a2 = acc2[q];
        #pragma unroll
        for (int m = 1; m < 32; m <<= 1) {
            a1 += __shfl_xor(a1, m);
            a2 += __shfl_xor(a2, m);
        }
        acc1[q] = a1; acc2[q] = a2;
    }
    if (r == 0) {
        // C/D layout: row = (q&3) + 8*(q>>2) + 4*(lane>>5)
        #pragma unroll
        for (int q = 0; q < 16; q++) {
            int grow = xrow0 + (q & 3) + 8 * (q >> 2) + 4 * h;
            atomicAdd(&S1[job * BN + grow], acc1[q]);
            atomicAdd(&S2[job * BN + grow], acc2[q]);
        }
    }
}

// ---------------- finalize: per-row loss terms -> weighted mean --------------
__global__ __launch_bounds__(256) void finalize_kernel(
    const float* __restrict__ S1, const float* __restrict__ S2,
    const float* __restrict__ d1, const float* __restrict__ d2,
    const float* __restrict__ d3, float* __restrict__ out)
{
    int idx = blockIdx.x * 256 + threadIdx.x;   // 0..16383
    float term = 0.f;
    const float EM2 = 0.13533528323661270f;     // e^-2
    if (idx < 8192) {                           // inter jobs 0/1
        int j = idx >> 12, i = idx & 4095;
        float dv = j ? d2[i] : d1[i];
        float n = 4095.f;
        float pos = __expf(2.f * dv);
        float s1 = S1[j * BN + i] - pos;
        float s2 = S2[j * BN + i] - pos * pos;
        float rw = s2 * n / s1;
        float ng = (-0.1f * n * pos + rw) * (1.f / 0.9f);
        ng = fmaxf(ng, n * EM2);
        term = logf((pos + ng) / pos) * (0.5f / 4096.f);
    } else {                                    // intra rows 0..8191
        int i = idx - 8192;
        int ii = i & 4095;
        int job = 2 + (i >> 12);
        float n = 8190.f;
        const float E2 = 7.3890560989306495f, E4 = 54.598150033144236f;
        float pos = __expf(2.f * d3[ii]);
        float s1 = S1[job * BN + ii] - E2 - pos;
        float s2 = S2[job * BN + ii] - E4 - pos * pos;
        float rw = s2 * n / s1;
        float ng = (-0.1f * n * pos + rw) * (1.f / 0.9f);
        ng = fmaxf(ng, n * EM2);
        term = logf((pos + ng) / pos) * (1.f / 8192.f);
    }

    #pragma unroll
    for (int m = 1; m < 64; m <<= 1) term += __shfl_xor(term, m);
    __shared__ float sm[4];
    int wid = threadIdx.x >> 6;
    if ((threadIdx.x & 63) == 0) sm[wid] = term;
    __syncthreads();
    if (threadIdx.x == 0) atomicAdd(out, sm[0] + sm[1] + sm[2] + sm[3]);
}

extern "C" void kernel_launch(void* const* d_in, const int* in_sizes, int n_in,
                              void* d_out, int out_size, void* d_ws, size_t ws_size,
                              hipStream_t stream)
{
    const float* z1   = (const float*)d_in[0];
    const float* z2   = (const float*)d_in[1];
    // d_in[2] = text_z : unused by the reference
    const float* attr = (const float*)d_in[3];
    const int*   uni  = (const int*)d_in[4];
    float* out = (float*)d_out;

    char* ws = (char*)d_ws;
    size_t mat = (size_t)BN * DD;                    // elements per matrix
    __hip_bfloat16* Z1b = (__hip_bfloat16*)ws;
    __hip_bfloat16* Z2b = Z1b + mat;
    __hip_bfloat16* G1b = Z2b + mat;
    __hip_bfloat16* G2b = G1b + mat;
    __hip_bfloat16* Ab  = G2b + mat;
    float* S1 = (float*)(ws + 5 * mat * sizeof(__hip_bfloat16));
    float* S2 = S1 + 4 * BN;
    float* d1 = S2 + 4 * BN;
    float* d2 = d1 + BN;
    float* d3 = d2 + BN;

    prep_kernel<<<BN, 64, 0, stream>>>(z1, z2, attr, uni,
                                       Z1b, Z2b, G1b, G2b, Ab,
                                       d1, d2, d3, S1, S2, out);
    rowsum_kernel<<<dim3(128, 24), 64, 0, stream>>>(Z1b, Z2b, G1b, G2b, Ab, S1, S2);
    finalize_kernel<<<64, 256, 0, stream>>>(S1, S2, d1, d2, d3, out);
}

// Round 2
// 53.403 us; speedup vs baseline: 2.0472x; 2.0472x over previous
//
#include <hip/hip_runtime.h>
#include <hip/hip_bf16.h>

#define BN 4096
#define DD 128
#define NTILES 16   // 16 tiles x 64 cols = 1024-col chunk per block

typedef __bf16 bf16x8 __attribute__((ext_vector_type(8)));
typedef float f32x16 __attribute__((ext_vector_type(16)));

__device__ __forceinline__ void gload_lds16(const void* g, void* l) {
    __builtin_amdgcn_global_load_lds(
        (const __attribute__((address_space(1))) void*)g,
        (__attribute__((address_space(3))) void*)l, 16, 0, 0);
}

// ---------------- prep: f32 -> bf16 (with gather), diag dots, zero accums ----
__global__ __launch_bounds__(64) void prep_kernel(
    const float* __restrict__ z1, const float* __restrict__ z2,
    const float* __restrict__ attr, const int* __restrict__ uni,
    __hip_bfloat16* __restrict__ Z1b, __hip_bfloat16* __restrict__ Z2b,
    __hip_bfloat16* __restrict__ G1b, __hip_bfloat16* __restrict__ G2b,
    __hip_bfloat16* __restrict__ Ab,
    float* __restrict__ d1, float* __restrict__ d2, float* __restrict__ d3,
    float* __restrict__ S1, float* __restrict__ S2, float* __restrict__ out)
{
    int r = blockIdx.x;
    int t = threadIdx.x;
    int gid = r * 64 + t;
    if (gid < 4 * BN) { S1[gid] = 0.f; S2[gid] = 0.f; }
    if (gid == 0) out[0] = 0.f;

    int au = uni[r];
    float p1 = 0.f, p2 = 0.f, p3 = 0.f;
    #pragma unroll
    for (int e = t; e < DD; e += 64) {
        float v1 = z1[(size_t)r * DD + e];
        float v2 = z2[(size_t)r * DD + e];
        float ga = attr[(size_t)au * DD + e];
        float g1 = z1[(size_t)au * DD + e];
        float g2 = z2[(size_t)au * DD + e];
        Z1b[(size_t)r * DD + e] = __float2bfloat16(v1);
        Z2b[(size_t)r * DD + e] = __float2bfloat16(v2);
        G1b[(size_t)r * DD + e] = __float2bfloat16(g1);
        G2b[(size_t)r * DD + e] = __float2bfloat16(g2);
        Ab [(size_t)r * DD + e] = __float2bfloat16(ga);
        p1 += g1 * ga; p2 += g2 * ga; p3 += v1 * v2;
    }
    #pragma unroll
    for (int m = 1; m < 64; m <<= 1) {
        p1 += __shfl_xor(p1, m);
        p2 += __shfl_xor(p2, m);
        p3 += __shfl_xor(p3, m);
    }
    if (t == 0) { d1[r] = p1; d2[r] = p2; d3[r] = p3; }
}

// ---------------- rowsum: fused sim + exp row-sum over 4 jobs ----------------
// job 0: X=G1b vs Y=Ab        (4096 cols)
// job 1: X=G2b vs Y=Ab        (4096 cols)
// job 2: X=Z1b vs Y={Z1b,Z2b} (8192 cols)
// job 3: X=Z2b vs Y={Z1b,Z2b} (8192 cols)
// Block: 4 waves x 32 X-rows = 128 rows; Y-tiles (64 rows x 256B) shared via
// double-buffered LDS, staged with global_load_lds (linear dest, pre-swizzled
// global source; reads apply the same XOR swizzle -> ~4-way residual conflict).
__global__ __launch_bounds__(256, 3) void rowsum_kernel(
    const __hip_bfloat16* __restrict__ Z1b, const __hip_bfloat16* __restrict__ Z2b,
    const __hip_bfloat16* __restrict__ G1b, const __hip_bfloat16* __restrict__ G2b,
    const __hip_bfloat16* __restrict__ Ab,
    float* __restrict__ S1, float* __restrict__ S2)
{
    int rowblk = blockIdx.x;   // 0..31 : 128 X-rows each
    int chunk  = blockIdx.y;   // 0..23 : 1024 Y-rows each

    int job;
    const __hip_bfloat16 *X, *Y;
    int ybase;
    if (chunk < 4)       { job = 0; X = G1b; Y = Ab; ybase = chunk * 1024; }
    else if (chunk < 8)  { job = 1; X = G2b; Y = Ab; ybase = (chunk - 4) * 1024; }
    else if (chunk < 16) { job = 2; X = Z1b; int c = chunk - 8;  ybase = c * 1024;
                           Y = (ybase < BN) ? Z1b : Z2b; if (ybase >= BN) ybase -= BN; }
    else                 { job = 3; X = Z2b; int c = chunk - 16; ybase = c * 1024;
                           Y = (ybase < BN) ? Z1b : Z2b; if (ybase >= BN) ybase -= BN; }

    __shared__ char lds[2 * 16384];   // double-buffered 64-row Y tiles

    int tid  = threadIdx.x;
    int wid  = tid >> 6;      // 0..3
    int lane = tid & 63;
    int r = lane & 31, h = lane >> 5;

    // A fragments: held in registers for the whole sweep.
    // v_mfma_f32_32x32x16_bf16 A/B layout: row = lane&31, k = 16*s + 8*(lane>>5) + j
    int xrow0 = rowblk * 128 + wid * 32;
    const __hip_bfloat16* xrow = X + (size_t)(xrow0 + r) * DD + 8 * h;
    bf16x8 afrag[8];
    #pragma unroll
    for (int s = 0; s < 8; s++)
        afrag[s] = *reinterpret_cast<const bf16x8*>(xrow + 16 * s);

    // Staging: 64 rows x 16 granules(16B). LDS linear granule g holds content
    // granule (g&15) ^ ((g>>4)&7) of row g>>4  (inverse-swizzled source).
    int soff[4];
    #pragma unroll
    for (int i = 0; i < 4; i++) {
        int g = wid * 256 + i * 64 + lane;
        int row = g >> 4, cs = g & 15;
        soff[i] = row * 256 + ((cs ^ (row & 7)) << 4);
    }
    const char* Ychunk = (const char*)Y + (size_t)ybase * 256;

    // Read offsets: content granule c = 2s+h of row r lives at slot c^(r&7).
    int roff[8];
    #pragma unroll
    for (int s = 0; s < 8; s++)
        roff[s] = r * 256 + (((2 * s + h) ^ (r & 7)) << 4);

    float acc1[16], acc2[16];
    #pragma unroll
    for (int q = 0; q < 16; q++) { acc1[q] = 0.f; acc2[q] = 0.f; }

    auto stage = [&](int b, int ct) {
        const char* gsrc = Ychunk + (size_t)ct * 16384;
        #pragma unroll
        for (int i = 0; i < 4; i++)
            gload_lds16(gsrc + soff[i], lds + b * 16384 + ((wid * 256 + i * 64) << 4));
    };

    stage(0, 0);
    __syncthreads();
    int cur = 0;
    for (int ct = 0; ct < NTILES; ct++) {
        if (ct + 1 < NTILES) stage(cur ^ 1, ct + 1);   // prefetch next tile
        #pragma unroll
        for (int G = 0; G < 2; G++) {                  // two 32-col groups
            f32x16 cacc;
            #pragma unroll
            for (int q = 0; q < 16; q++) cacc[q] = 0.f;
            #pragma unroll
            for (int s = 0; s < 8; s++) {
                bf16x8 bfrag = *reinterpret_cast<const bf16x8*>(
                    lds + cur * 16384 + G * 8192 + roff[s]);
                cacc = __builtin_amdgcn_mfma_f32_32x32x16_bf16(afrag[s], bfrag, cacc, 0, 0, 0);
            }
            // sim = dot/TEMP = 2*dot ; e1 = exp(sim); e1^2 = exp(2*sim)
            #pragma unroll
            for (int q = 0; q < 16; q++) {
                float e1 = __expf(2.0f * cacc[q]);
                acc1[q] += e1;
                acc2[q] = fmaf(e1, e1, acc2[q]);
            }
        }
        __syncthreads();
        cur ^= 1;
    }

    // Reduce over the 32 lanes sharing each output row
    #pragma unroll
    for (int q = 0; q < 16; q++) {
        float a1 = acc1[q], a2 = acc2[q];
        #pragma unroll
        for (int m = 1; m < 32; m <<= 1) {
            a1 += __shfl_xor(a1, m);
            a2 += __shfl_xor(a2, m);
        }
        acc1[q] = a1; acc2[q] = a2;
    }
    if (r == 0) {
        // C/D layout: col = lane&31, row = (q&3) + 8*(q>>2) + 4*(lane>>5)
        #pragma unroll
        for (int q = 0; q < 16; q++) {
            int grow = xrow0 + (q & 3) + 8 * (q >> 2) + 4 * h;
            atomicAdd(&S1[job * BN + grow], acc1[q]);
            atomicAdd(&S2[job * BN + grow], acc2[q]);
        }
    }
}

// ---------------- finalize: per-row loss terms -> weighted mean --------------
__global__ __launch_bounds__(256) void finalize_kernel(
    const float* __restrict__ S1, const float* __restrict__ S2,
    const float* __restrict__ d1, const float* __restrict__ d2,
    const float* __restrict__ d3, float* __restrict__ out)
{
    int idx = blockIdx.x * 256 + threadIdx.x;   // 0..16383
    float term = 0.f;
    const float EM2 = 0.13533528323661270f;     // e^-2
    if (idx < 8192) {                           // inter jobs 0/1
        int j = idx >> 12, i = idx & 4095;
        float dv = j ? d2[i] : d1[i];
        float n = 4095.f;
        float pos = __expf(2.f * dv);
        float s1 = S1[j * BN + i] - pos;
        float s2 = S2[j * BN + i] - pos * pos;
        float rw = s2 * n / s1;
        float ng = (-0.1f * n * pos + rw) * (1.f / 0.9f);
        ng = fmaxf(ng, n * EM2);
        term = logf((pos + ng) / pos) * (0.5f / 4096.f);
    } else {                                    // intra rows 0..8191
        int i = idx - 8192;
        int ii = i & 4095;
        int job = 2 + (i >> 12);
        float n = 8190.f;
        const float E2 = 7.3890560989306495f, E4 = 54.598150033144236f;
        float pos = __expf(2.f * d3[ii]);
        float s1 = S1[job * BN + ii] - E2 - pos;
        float s2 = S2[job * BN + ii] - E4 - pos * pos;
        float rw = s2 * n / s1;
        float ng = (-0.1f * n * pos + rw) * (1.f / 0.9f);
        ng = fmaxf(ng, n * EM2);
        term = logf((pos + ng) / pos) * (1.f / 8192.f);
    }

    #pragma unroll
    for (int m = 1; m < 64; m <<= 1) term += __shfl_xor(term, m);
    __shared__ float sm[4];
    int wid = threadIdx.x >> 6;
    if ((threadIdx.x & 63) == 0) sm[wid] = term;
    __syncthreads();
    if (threadIdx.x == 0) atomicAdd(out, sm[0] + sm[1] + sm[2] + sm[3]);
}

extern "C" void kernel_launch(void* const* d_in, const int* in_sizes, int n_in,
                              void* d_out, int out_size, void* d_ws, size_t ws_size,
                              hipStream_t stream)
{
    const float* z1   = (const float*)d_in[0];
    const float* z2   = (const float*)d_in[1];
    // d_in[2] = text_z : unused by the reference
    const float* attr = (const float*)d_in[3];
    const int*   uni  = (const int*)d_in[4];
    float* out = (float*)d_out;

    char* ws = (char*)d_ws;
    size_t mat = (size_t)BN * DD;                    // elements per matrix
    __hip_bfloat16* Z1b = (__hip_bfloat16*)ws;
    __hip_bfloat16* Z2b = Z1b + mat;
    __hip_bfloat16* G1b = Z2b + mat;
    __hip_bfloat16* G2b = G1b + mat;
    __hip_bfloat16* Ab  = G2b + mat;
    float* S1 = (float*)(ws + 5 * mat * sizeof(__hip_bfloat16));
    float* S2 = S1 + 4 * BN;
    float* d1 = S2 + 4 * BN;
    float* d2 = d1 + BN;
    float* d3 = d2 + BN;

    prep_kernel<<<BN, 64, 0, stream>>>(z1, z2, attr, uni,
                                       Z1b, Z2b, G1b, G2b, Ab,
                                       d1, d2, d3, S1, S2, out);
    rowsum_kernel<<<dim3(32, 24), 256, 0, stream>>>(Z1b, Z2b, G1b, G2b, Ab, S1, S2);
    finalize_kernel<<<64, 256, 0, stream>>>(S1, S2, d1, d2, d3, out);
}